// Round 8
// baseline (312.840 us; speedup 1.0000x reference)
//
#include <hip/hip_runtime.h>

#define NEMB 512
#define EMB 64
#define BSTR 262144          // 64*4096
#define DECAYF 0.99f
#define OMDF 0.01f
#define EPSF 1e-5f
#define GAP_T 0.04f

typedef __attribute__((ext_vector_type(8))) short bf16x8;
typedef __attribute__((ext_vector_type(4))) float f32x4;

__device__ __forceinline__ unsigned short f2bf(float f) {
    unsigned u = __float_as_uint(f);
    return (unsigned short)((u + 0x7FFFu + ((u >> 16) & 1u)) >> 16);   // RNE
}
__device__ __forceinline__ float bf2f(unsigned short h) {
    return __uint_as_float(((unsigned)h) << 16);
}

// 9 blocks x 512 threads.
// blocks 0-7: split w into bf16 hi/lo transposed [n][k].
// block 8: wsq + zero flagcnt + zero cnt_ws (512) + zero es region (32768).
__global__ void prep_kernel(const float* __restrict__ w,
                            unsigned short* __restrict__ wh, unsigned short* __restrict__ wl,
                            float* __restrict__ wsq, unsigned* __restrict__ flagcnt,
                            float* __restrict__ cnt_ws, float* __restrict__ es_region) {
    int j = threadIdx.x;
    if (blockIdx.x < 8) {
        int d0 = blockIdx.x << 3;
        bf16x8 hb, lb;
#pragma unroll
        for (int i = 0; i < 8; ++i) {
            float v = w[(d0 + i) * NEMB + j];
            unsigned short h = f2bf(v);
            hb[i] = (short)h;
            lb[i] = (short)f2bf(v - bf2f(h));
        }
        *(bf16x8*)(wh + j * EMB + d0) = hb;
        *(bf16x8*)(wl + j * EMB + d0) = lb;
    } else {
        float s = 0.f;
#pragma unroll
        for (int d = 0; d < EMB; ++d) { float v = w[d * NEMB + j]; s = fmaf(v, v, s); }
        wsq[j] = s;
        cnt_ws[j] = 0.f;
        if (j == 0) *flagcnt = 0u;
#pragma unroll
        for (int k = j; k < 32768; k += 512) es_region[k] = 0.f;
    }
}

#define UPD(S1, J1, S2, J2, s_, j_) do { \
    if (s_ < S1 || (s_ == S1 && j_ < J1)) { S2 = S1; J2 = J1; S1 = s_; J1 = j_; } \
    else if (s_ < S2 || (s_ == S2 && j_ < J2)) { S2 = s_; J2 = j_; } } while (0)

// block = 64 tokens (1 h-row), 4 waves. Wave = 32 tokens x 256 codes (16 iters).
// Packed u32 keys: rounded (128 + wq - 2*dot) bits | 9-bit j. ||x||^2 cancels.
// 19.5 KB LDS, 6 blocks/CU target.
__global__ __launch_bounds__(256, 6) void vq_main(
    const float* __restrict__ x,
    const unsigned short* __restrict__ wh, const unsigned short* __restrict__ wl,
    const float* __restrict__ wsq,
    float* __restrict__ out_arg,
    unsigned* __restrict__ flagcnt, unsigned* __restrict__ flaglist)
{
    __shared__ __align__(16) float xt[EMB * 64];    // [d][m] 16 KB
    __shared__ float wsq_s[NEMB];                   // wq + 128 (bias keeps keys positive)
    __shared__ unsigned ksc[2][64][2];              // per-half merged (k1,k2) per token

    const int tid = threadIdx.x;
    const int blk = blockIdx.x;          // 2048
    const int b  = blk >> 6;
    const int h  = blk & 63;
    const int t0 = b * 4096 + h * 64;
    const float* xbase = x + b * BSTR + h * 64;

#pragma unroll
    for (int it = 0; it < 4; ++it) {
        int idx = tid + (it << 8);       // float4 idx 0..1023
        int d = idx >> 4, q = idx & 15;
        float4 v = *(const float4*)(xbase + d * 4096 + (q << 2));
        *(float4*)(xt + (d << 6) + (q << 2)) = v;
    }
    wsq_s[tid] = wsq[tid] + 128.f;
    wsq_s[tid + 256] = wsq[tid + 256] + 128.f;
    __syncthreads();

    const int lane = tid & 63;
    const int wave = tid >> 6;
    const int tg   = wave >> 1;          // token group (0,1)
    const int ch   = wave & 1;           // code half (0,1)
    const int l15  = lane & 15;
    const int quad = lane >> 4;
    const int wbase = tg << 5;           // 32 tokens per wave
    const int n0 = ch << 8;              // 256 codes per wave

    // A fragments (hi/lo), reused across all 16 code iterations
    bf16x8 ah[2][2], al[2][2];
#pragma unroll
    for (int mt = 0; mt < 2; ++mt) {
        int m = wbase + (mt << 4) + l15;
#pragma unroll
        for (int ks = 0; ks < 2; ++ks) {
            int k0 = (ks << 5) + (quad << 3);
            bf16x8 hh, ll;
#pragma unroll
            for (int i = 0; i < 8; ++i) {
                float v = xt[((k0 + i) << 6) + m];
                unsigned short hv = f2bf(v);
                hh[i] = (short)hv;
                ll[i] = (short)f2bf(v - bf2f(hv));
            }
            ah[mt][ks] = hh; al[mt][ks] = ll;
        }
    }

    unsigned k1[2][4], k2[2][4];
#pragma unroll
    for (int mt = 0; mt < 2; ++mt)
#pragma unroll
        for (int r = 0; r < 4; ++r) { k1[mt][r] = 0xFFFFFFFFu; k2[mt][r] = 0xFFFFFFFFu; }

    const int qoff = quad << 3;
#pragma unroll 2
    for (int it = 0; it < 16; ++it) {
        const int n = n0 + (it << 4) + l15;
        const unsigned short* ph = wh + n * EMB + qoff;
        const unsigned short* pl = wl + n * EMB + qoff;
        bf16x8 b0 = *(const bf16x8*)(ph);
        bf16x8 b1 = *(const bf16x8*)(ph + 32);
        bf16x8 b2 = *(const bf16x8*)(pl);
        bf16x8 b3 = *(const bf16x8*)(pl + 32);
        float wq = wsq_s[n];

        f32x4 acc0 = (f32x4){0.f, 0.f, 0.f, 0.f};
        f32x4 acc1 = (f32x4){0.f, 0.f, 0.f, 0.f};
        acc0 = __builtin_amdgcn_mfma_f32_16x16x32_bf16(ah[0][0], b0, acc0, 0, 0, 0);
        acc1 = __builtin_amdgcn_mfma_f32_16x16x32_bf16(ah[1][0], b0, acc1, 0, 0, 0);
        acc0 = __builtin_amdgcn_mfma_f32_16x16x32_bf16(ah[0][1], b1, acc0, 0, 0, 0);
        acc1 = __builtin_amdgcn_mfma_f32_16x16x32_bf16(ah[1][1], b1, acc1, 0, 0, 0);
        acc0 = __builtin_amdgcn_mfma_f32_16x16x32_bf16(ah[0][0], b2, acc0, 0, 0, 0);
        acc1 = __builtin_amdgcn_mfma_f32_16x16x32_bf16(ah[1][0], b2, acc1, 0, 0, 0);
        acc0 = __builtin_amdgcn_mfma_f32_16x16x32_bf16(ah[0][1], b3, acc0, 0, 0, 0);
        acc1 = __builtin_amdgcn_mfma_f32_16x16x32_bf16(ah[1][1], b3, acc1, 0, 0, 0);
        acc0 = __builtin_amdgcn_mfma_f32_16x16x32_bf16(al[0][0], b0, acc0, 0, 0, 0);
        acc1 = __builtin_amdgcn_mfma_f32_16x16x32_bf16(al[1][0], b0, acc1, 0, 0, 0);
        acc0 = __builtin_amdgcn_mfma_f32_16x16x32_bf16(al[0][1], b1, acc0, 0, 0, 0);
        acc1 = __builtin_amdgcn_mfma_f32_16x16x32_bf16(al[1][1], b1, acc1, 0, 0, 0);

#pragma unroll
        for (int r = 0; r < 4; ++r) {
            float s0 = fmaf(-2.f, acc0[r], wq);
            unsigned key0 = ((__float_as_uint(s0) + 0x100u) & 0xFFFFFE00u) | (unsigned)n;
            unsigned mx0 = max(k1[0][r], key0);
            k1[0][r] = min(k1[0][r], key0);
            k2[0][r] = min(k2[0][r], mx0);

            float s1 = fmaf(-2.f, acc1[r], wq);
            unsigned key1 = ((__float_as_uint(s1) + 0x100u) & 0xFFFFFE00u) | (unsigned)n;
            unsigned mx1 = max(k1[1][r], key1);
            k1[1][r] = min(k1[1][r], key1);
            k2[1][r] = min(k2[1][r], mx1);
        }
    }

    // butterfly merge over the 16 l15-lanes, then park per-half result in LDS
#pragma unroll
    for (int mt = 0; mt < 2; ++mt)
#pragma unroll
        for (int r = 0; r < 4; ++r) {
            unsigned a1 = k1[mt][r], a2 = k2[mt][r];
#pragma unroll
            for (int msk = 1; msk < 16; msk <<= 1) {
                unsigned o1 = __shfl_xor(a1, msk, 64);
                unsigned o2 = __shfl_xor(a2, msk, 64);
                unsigned mx = max(a1, o1);
                a1 = min(a1, o1);
                a2 = min(min(a2, o2), mx);
            }
            if (l15 == 0) {
                int tk = wbase + (mt << 4) + (quad << 2) + r;
                ksc[ch][tk][0] = a1;
                ksc[ch][tk][1] = a2;
            }
        }
    __syncthreads();

    // final cross-half merge: one thread per token
    if (tid < 64) {
        unsigned a1 = ksc[0][tid][0], a2 = ksc[0][tid][1];
        unsigned c1 = ksc[1][tid][0], c2 = ksc[1][tid][1];
        unsigned mx = max(a1, c1);
        unsigned m1 = min(a1, c1);
        unsigned m2 = min(min(a2, c2), mx);
        int j = (int)(m1 & 511u);
        out_arg[t0 + tid] = (float)j;
        float g1 = __uint_as_float(m1 & 0xFFFFFE00u);
        float g2 = __uint_as_float(m2 & 0xFFFFFE00u);
        if (g2 - g1 < GAP_T) {
            unsigned idx = atomicAdd(flagcnt, 1u);
            if (idx < 131072u) flaglist[idx] = (unsigned)(t0 + tid);
        }
    }
}

// wave-per-4-tokens exact fp32 (+f64 tie) re-decision; fixes out_arg only.
__global__ __launch_bounds__(256) void refine_kernel(
    const float* __restrict__ x, const float* __restrict__ w, const float* __restrict__ wsq,
    const unsigned* __restrict__ flagcnt, const unsigned* __restrict__ flaglist,
    float* __restrict__ out_arg)
{
    const unsigned count = min(*flagcnt, 131072u);
    if (count == 0) return;
    const int lane = threadIdx.x & 63;
    const unsigned gw = (blockIdx.x << 2) + (unsigned)(threadIdx.x >> 6);
    const unsigned nw = gridDim.x << 2;
    const unsigned ng4 = (count + 3) >> 2;

    for (unsigned g4 = gw; g4 < ng4; g4 += nw) {
        unsigned base = g4 << 2;
        unsigned tks[4];
        float xd[4], xq[4];
#pragma unroll
        for (int u = 0; u < 4; ++u) {
            unsigned idx = base + (unsigned)u;
            if (idx >= count) idx = count - 1;
            unsigned t = flaglist[idx];
            tks[u] = t;
            xd[u] = x[(t >> 12) * BSTR + lane * 4096 + (t & 4095u)];
            xq[u] = xd[u] * xd[u];
        }
#pragma unroll
        for (int m = 1; m < 64; m <<= 1) {
#pragma unroll
            for (int u = 0; u < 4; ++u) xq[u] += __shfl_xor(xq[u], m, 64);
        }

        float accv[4][8];
#pragma unroll
        for (int u = 0; u < 4; ++u)
#pragma unroll
            for (int k = 0; k < 8; ++k) accv[u][k] = 0.f;

#pragma unroll 4
        for (int d = 0; d < EMB; ++d) {
            float4 wa = *(const float4*)(w + d * NEMB + (lane << 2));
            float4 wb = *(const float4*)(w + d * NEMB + 256 + (lane << 2));
            float wr[8] = {wa.x, wa.y, wa.z, wa.w, wb.x, wb.y, wb.z, wb.w};
#pragma unroll
            for (int u = 0; u < 4; ++u) {
                float xv = __shfl(xd[u], d, 64);
#pragma unroll
                for (int k = 0; k < 8; ++k) accv[u][k] = fmaf(xv, wr[k], accv[u][k]);
            }
        }

#pragma unroll
        for (int u = 0; u < 4; ++u) {
            float S1 = 3.4e38f, S2 = 3.4e38f; int J1 = 0, J2 = 0;
#pragma unroll
            for (int k = 0; k < 8; ++k) {
                int j = (k < 4) ? ((lane << 2) + k) : (256 + (lane << 2) + k - 4);
                float s = (xq[u] - 2.f * accv[u][k]) + wsq[j];
                UPD(S1, J1, S2, J2, s, j);
            }
#pragma unroll
            for (int m = 1; m < 64; m <<= 1) {
                float os1 = __shfl_xor(S1, m, 64); int oj1 = __shfl_xor(J1, m, 64);
                float os2 = __shfl_xor(S2, m, 64); int oj2 = __shfl_xor(J2, m, 64);
                UPD(S1, J1, S2, J2, os1, oj1);
                UPD(S1, J1, S2, J2, os2, oj2);
            }

            int jm = J1;
            if (S2 - S1 < 1e-3f) {
                float w1 = w[lane * NEMB + J1];
                float w2 = w[lane * NEMB + J2];
                double e1 = (double)w1 * (double)w1 - 2.0 * (double)xd[u] * (double)w1;
                double e2 = (double)w2 * (double)w2 - 2.0 * (double)xd[u] * (double)w2;
#pragma unroll
                for (int m = 1; m < 64; m <<= 1) {
                    e1 += __shfl_xor(e1, m, 64);
                    e2 += __shfl_xor(e2, m, 64);
                }
                if (e2 < e1 || (e2 == e1 && J2 < J1)) jm = J2;
            }
            if (lane == 0 && (base + (unsigned)u) < count) out_arg[tks[u]] = (float)jm;
        }
    }
}

// fused: result write + es/cnt accumulation. grid = 65 grp x 32 chunks (2080 blocks).
// float4-vectorized over 4 consecutive tokens. LDS accumulate, atomic flush.
__global__ __launch_bounds__(256) void finish_kernel(
    const float* __restrict__ x, const float* __restrict__ w, const float* __restrict__ arg,
    float* __restrict__ out_result,
    float* __restrict__ es, float* __restrict__ cnt)
{
    __shared__ float wrow[NEMB];
    __shared__ float acc[NEMB];
    const int tid = threadIdx.x;
    const int grp = blockIdx.x >> 5;     // 0..64
    const int chunk = blockIdx.x & 31;

    acc[tid] = 0.f; acc[tid + 256] = 0.f;
    if (grp < 64) {
        wrow[tid] = w[grp * NEMB + tid];
        wrow[tid + 256] = w[grp * NEMB + tid + 256];
    }
    __syncthreads();

    const int tbase = chunk << 12;       // 4096 tokens per chunk
    if (grp < 64) {
        const int d = grp;
#pragma unroll 2
        for (int it = 0; it < 4; ++it) {
            int t = tbase + (it << 10) + (tid << 2);      // 4 consecutive tokens, same b
            int o = (t >> 12) * BSTR + d * 4096 + (t & 4095);
            float4 a4 = *(const float4*)(arg + t);
            float4 x4 = *(const float4*)(x + o);
            int j0 = (int)a4.x, j1 = (int)a4.y, j2 = (int)a4.z, j3 = (int)a4.w;
            atomicAdd(&acc[j0], x4.x);
            atomicAdd(&acc[j1], x4.y);
            atomicAdd(&acc[j2], x4.z);
            atomicAdd(&acc[j3], x4.w);
            float4 r4 = {wrow[j0], wrow[j1], wrow[j2], wrow[j3]};
            *(float4*)(out_result + o) = r4;
        }
    } else {
#pragma unroll 2
        for (int it = 0; it < 4; ++it) {
            int t = tbase + (it << 10) + (tid << 2);
            float4 a4 = *(const float4*)(arg + t);
            atomicAdd(&acc[(int)a4.x], 1.0f);
            atomicAdd(&acc[(int)a4.y], 1.0f);
            atomicAdd(&acc[(int)a4.z], 1.0f);
            atomicAdd(&acc[(int)a4.w], 1.0f);
        }
    }
    __syncthreads();

    float* dst = (grp < 64) ? (es + grp * NEMB) : cnt;
#pragma unroll
    for (int k = 0; k < 2; ++k) {
        int j = tid + (k << 8);
        float v = acc[j];
        if (v != 0.f) atomicAdd(&dst[j], v);
    }
}

// fused finalize: 64 blocks x 512 threads. Block d: computes ncs (redundant, cheap),
// reduces n, writes row d of new_weight/new_embed_avg; block 0 also writes out_ncs.
__global__ void finalize_kernel(const float* __restrict__ cs_in, const float* __restrict__ avg_in,
                                const float* __restrict__ cnt_ws,
                                float* __restrict__ out_w, float* __restrict__ out_ncs,
                                float* __restrict__ avg_io /* es in, new_embed_avg out */) {
    __shared__ float red[NEMB];
    const int j = threadIdx.x;
    const int d = blockIdx.x;
    float c = cnt_ws[j];
    float nidx = (c == 0.f) ? 1.f : c;
    float ncs = DECAYF * cs_in[j] + OMDF * nidx;
    red[j] = ncs;
    __syncthreads();
    for (int s = 256; s > 0; s >>= 1) {
        if (j < s) red[j] += red[j + s];
        __syncthreads();
    }
    float n = red[0];
    float csj = (ncs + EPSF) / (n + (float)NEMB * EPSF) * n;
    int o = d * NEMB + j;
    float esv = avg_io[o];
    float navg = DECAYF * avg_in[o] + OMDF * esv;
    avg_io[o] = navg;
    out_w[o] = navg / csj;
    if (d == 0) out_ncs[j] = ncs;
}

extern "C" void kernel_launch(void* const* d_in, const int* in_sizes, int n_in,
                              void* d_out, int out_size, void* d_ws, size_t ws_size,
                              hipStream_t stream) {
    (void)in_sizes; (void)n_in; (void)out_size; (void)ws_size;
    const float* x   = (const float*)d_in[0];
    const float* w   = (const float*)d_in[1];
    const float* cs  = (const float*)d_in[2];
    const float* avg = (const float*)d_in[3];

    float* out = (float*)d_out;
    float* out_result = out;                 // 8388608
    float* out_arg    = out + 8388608;       // 131072
    float* out_w      = out + 8519680;       // 32768
    float* out_ncs    = out + 8552448;       // 512
    float* out_avg    = out + 8552960;       // 32768 (es accumulates here)

    char* wsb = (char*)d_ws;
    unsigned short* wh = (unsigned short*)wsb;             // 65536 B
    unsigned short* wl = (unsigned short*)(wsb + 65536);   // 65536 B
    float* wsq      = (float*)(wsb + 131072);              // 2048 B
    float* cnt_ws   = (float*)(wsb + 133120);              // 2048 B (counts)
    unsigned* flagcnt = (unsigned*)(wsb + 135168);         // 4 B
    unsigned* flaglist = (unsigned*)(wsb + 135424);        // 524288 B

    prep_kernel<<<9, 512, 0, stream>>>(w, wh, wl, wsq, flagcnt, cnt_ws, out_avg);
    vq_main<<<2048, 256, 0, stream>>>(x, wh, wl, wsq, out_arg, flagcnt, flaglist);
    refine_kernel<<<128, 256, 0, stream>>>(x, w, wsq, flagcnt, flaglist, out_arg);
    finish_kernel<<<2080, 256, 0, stream>>>(x, w, out_arg, out_result, out_avg, cnt_ws);
    finalize_kernel<<<64, 512, 0, stream>>>(cs, avg, cnt_ws, out_w, out_ncs, out_avg);
}

// Round 9
// 211.671 us; speedup vs baseline: 1.4780x; 1.4780x over previous
//
#include <hip/hip_runtime.h>

#define NEMB 512
#define EMB 64
#define BSTR 262144          // 64*4096
#define DECAYF 0.99f
#define OMDF 0.01f
#define EPSF 1e-5f
#define GAP_T 0.012f

typedef __attribute__((ext_vector_type(8))) short bf16x8;
typedef __attribute__((ext_vector_type(4))) float f32x4;

__device__ __forceinline__ unsigned short f2bf(float f) {
    unsigned u = __float_as_uint(f);
    return (unsigned short)((u + 0x7FFFu + ((u >> 16) & 1u)) >> 16);   // RNE
}
__device__ __forceinline__ float bf2f(unsigned short h) {
    return __uint_as_float(((unsigned)h) << 16);
}

// 9 blocks x 512 threads.
// blocks 0-7: split w into bf16 hi/lo transposed [n][k].
// block 8: wsq + zero cnt_ws (512) + zero es region (32768).
__global__ void prep_kernel(const float* __restrict__ w,
                            unsigned short* __restrict__ wh, unsigned short* __restrict__ wl,
                            float* __restrict__ wsq,
                            float* __restrict__ cnt_ws, float* __restrict__ es_region) {
    int j = threadIdx.x;
    if (blockIdx.x < 8) {
        int d0 = blockIdx.x << 3;
        bf16x8 hb, lb;
#pragma unroll
        for (int i = 0; i < 8; ++i) {
            float v = w[(d0 + i) * NEMB + j];
            unsigned short h = f2bf(v);
            hb[i] = (short)h;
            lb[i] = (short)f2bf(v - bf2f(h));
        }
        *(bf16x8*)(wh + j * EMB + d0) = hb;
        *(bf16x8*)(wl + j * EMB + d0) = lb;
    } else {
        float s = 0.f;
#pragma unroll
        for (int d = 0; d < EMB; ++d) { float v = w[d * NEMB + j]; s = fmaf(v, v, s); }
        wsq[j] = s;
        cnt_ws[j] = 0.f;
#pragma unroll
        for (int k = j; k < 32768; k += 512) es_region[k] = 0.f;
    }
}

#define UPD(S1, J1, S2, J2, s_, j_) do { \
    if (s_ < S1 || (s_ == S1 && j_ < J1)) { S2 = S1; J2 = J1; S1 = s_; J1 = j_; } \
    else if (s_ < S2 || (s_ == S2 && j_ < J2)) { S2 = s_; J2 = j_; } } while (0)

// block = 128 tokens (2 h-rows), 4 waves x 32 tokens. Split-bf16 MFMA distances.
// Exact (v1,j1,v2) tracking. Flagged near-tie tokens refined INLINE (wave-per-token,
// exact fp32 + f64 tie) — no separate refine dispatch.
// 4 blocks/CU: bounds (256,4) = VGPR cap 128; r8's (256,6) cap 85 caused scratch
// spill (FETCH/WRITE 154/158 MB) — do not raise the occupancy bound.
__global__ __launch_bounds__(256, 4) void vq_main(
    const float* __restrict__ x, const float* __restrict__ w,
    const unsigned short* __restrict__ wh, const unsigned short* __restrict__ wl,
    const float* __restrict__ wsq,
    float* __restrict__ out_arg)
{
    __shared__ __align__(16) float xt[EMB * 128];   // [d][m] 32 KB
    __shared__ float xsq_s[128];
    __shared__ float wsq_s[NEMB];
    __shared__ int flg[128];
    __shared__ int nflg;

    const int tid = threadIdx.x;
    const int blk = blockIdx.x;          // 1024
    const int b  = blk >> 5;
    const int h0 = (blk & 31) << 1;      // 2 rows
    const int t0 = b * 4096 + h0 * 64;   // global token base
    const float* xbase = x + b * BSTR + h0 * 64;

    if (tid == 0) nflg = 0;

#pragma unroll
    for (int it = 0; it < 8; ++it) {
        int idx = tid + (it << 8);       // float4 idx 0..2047
        int d = idx >> 5, q = idx & 31;
        float4 v = *(const float4*)(xbase + d * 4096 + (q << 2));
        *(float4*)(xt + d * 128 + (q << 2)) = v;
    }
    wsq_s[tid] = wsq[tid];
    wsq_s[tid + 256] = wsq[tid + 256];
    __syncthreads();

    if (tid < 128) {
        float s = 0.f;
#pragma unroll
        for (int d = 0; d < EMB; ++d) { float v = xt[d * 128 + tid]; s = fmaf(v, v, s); }
        xsq_s[tid] = s;
    }
    __syncthreads();

    const int lane = tid & 63;
    const int wave = tid >> 6;
    const int l15  = lane & 15;
    const int quad = lane >> 4;
    const int wbase = wave << 5;         // 32 tokens per wave

    // A fragments once (hi/lo), reused across all code chunks
    bf16x8 ah[2][2], al[2][2];
#pragma unroll
    for (int mt = 0; mt < 2; ++mt) {
        int m = wbase + (mt << 4) + l15;
#pragma unroll
        for (int ks = 0; ks < 2; ++ks) {
            int k0 = (ks << 5) + (quad << 3);
            bf16x8 hh, ll;
#pragma unroll
            for (int i = 0; i < 8; ++i) {
                float v = xt[(k0 + i) * 128 + m];
                unsigned short h = f2bf(v);
                hh[i] = (short)h;
                ll[i] = (short)f2bf(v - bf2f(h));
            }
            ah[mt][ks] = hh; al[mt][ks] = ll;
        }
    }

    float xq[2][4];
#pragma unroll
    for (int mt = 0; mt < 2; ++mt)
#pragma unroll
        for (int r = 0; r < 4; ++r)
            xq[mt][r] = xsq_s[wbase + (mt << 4) + (quad << 2) + r];

    float v1[2][4], v2[2][4];
    int   j1[2][4];
#pragma unroll
    for (int mt = 0; mt < 2; ++mt)
#pragma unroll
        for (int r = 0; r < 4; ++r) { v1[mt][r] = 3.4e38f; v2[mt][r] = 3.4e38f; j1[mt][r] = 0; }

#pragma unroll 2
    for (int it = 0; it < 32; ++it) {
        const int n = (it << 4) + l15;
        const unsigned short* ph = wh + n * EMB + (quad << 3);
        const unsigned short* pl = wl + n * EMB + (quad << 3);
        bf16x8 b0 = *(const bf16x8*)(ph);
        bf16x8 b1 = *(const bf16x8*)(ph + 32);
        bf16x8 b2 = *(const bf16x8*)(pl);
        bf16x8 b3 = *(const bf16x8*)(pl + 32);
        float wq = wsq_s[n];

        f32x4 acc0 = (f32x4){0.f, 0.f, 0.f, 0.f};
        f32x4 acc1 = (f32x4){0.f, 0.f, 0.f, 0.f};
        acc0 = __builtin_amdgcn_mfma_f32_16x16x32_bf16(ah[0][0], b0, acc0, 0, 0, 0);
        acc1 = __builtin_amdgcn_mfma_f32_16x16x32_bf16(ah[1][0], b0, acc1, 0, 0, 0);
        acc0 = __builtin_amdgcn_mfma_f32_16x16x32_bf16(ah[0][1], b1, acc0, 0, 0, 0);
        acc1 = __builtin_amdgcn_mfma_f32_16x16x32_bf16(ah[1][1], b1, acc1, 0, 0, 0);
        acc0 = __builtin_amdgcn_mfma_f32_16x16x32_bf16(ah[0][0], b2, acc0, 0, 0, 0);
        acc1 = __builtin_amdgcn_mfma_f32_16x16x32_bf16(ah[1][0], b2, acc1, 0, 0, 0);
        acc0 = __builtin_amdgcn_mfma_f32_16x16x32_bf16(ah[0][1], b3, acc0, 0, 0, 0);
        acc1 = __builtin_amdgcn_mfma_f32_16x16x32_bf16(ah[1][1], b3, acc1, 0, 0, 0);
        acc0 = __builtin_amdgcn_mfma_f32_16x16x32_bf16(al[0][0], b0, acc0, 0, 0, 0);
        acc1 = __builtin_amdgcn_mfma_f32_16x16x32_bf16(al[1][0], b0, acc1, 0, 0, 0);
        acc0 = __builtin_amdgcn_mfma_f32_16x16x32_bf16(al[0][1], b1, acc0, 0, 0, 0);
        acc1 = __builtin_amdgcn_mfma_f32_16x16x32_bf16(al[1][1], b1, acc1, 0, 0, 0);

#pragma unroll
        for (int r = 0; r < 4; ++r) {
            float s0 = fmaf(-2.f, acc0[r], xq[0][r] + wq);
            bool p0 = s0 < v1[0][r];
            float mx0 = fmaxf(s0, v1[0][r]);
            v1[0][r] = fminf(s0, v1[0][r]);
            v2[0][r] = fminf(v2[0][r], mx0);
            j1[0][r] = p0 ? n : j1[0][r];

            float s1 = fmaf(-2.f, acc1[r], xq[1][r] + wq);
            bool p1 = s1 < v1[1][r];
            float mx1 = fmaxf(s1, v1[1][r]);
            v1[1][r] = fminf(s1, v1[1][r]);
            v2[1][r] = fminf(v2[1][r], mx1);
            j1[1][r] = p1 ? n : j1[1][r];
        }
    }

    // butterfly merge (v1,j1,v2) across the 16 lanes sharing each token
#pragma unroll
    for (int mt = 0; mt < 2; ++mt)
#pragma unroll
        for (int r = 0; r < 4; ++r) {
            float a1 = v1[mt][r], a2 = v2[mt][r];
            int   aj = j1[mt][r];
#pragma unroll
            for (int msk = 1; msk < 16; msk <<= 1) {
                float o1 = __shfl_xor(a1, msk, 64);
                int   oj = __shfl_xor(aj, msk, 64);
                float o2 = __shfl_xor(a2, msk, 64);
                bool take = (o1 < a1) || (o1 == a1 && oj < aj);
                float mx = fmaxf(a1, o1);
                a2 = fminf(fminf(a2, o2), mx);
                a1 = fminf(a1, o1);
                aj = take ? oj : aj;
            }
            v1[mt][r] = a1; v2[mt][r] = a2; j1[mt][r] = aj;
        }

    if (l15 == 0) {
#pragma unroll
        for (int mt = 0; mt < 2; ++mt)
#pragma unroll
            for (int r = 0; r < 4; ++r) {
                int mlocal = wbase + (mt << 4) + (quad << 2) + r;
                out_arg[t0 + mlocal] = (float)j1[mt][r];
                if (v2[mt][r] - v1[mt][r] < GAP_T) {
                    int idx = atomicAdd(&nflg, 1);       // LDS atomic
                    flg[idx] = mlocal;
                }
            }
    }
    __syncthreads();

    // ---- inline refine: wave-per-token exact fp32 (+f64 tie) over flagged tokens ----
    const int nf = nflg;
    for (int g = wave; g < nf; g += 4) {
        const int m = flg[g];
        // x column from LDS (64-way bank-conflict read, once per token — negligible)
        float xd = xt[lane * 128 + m];
        float xqv = xd * xd;
#pragma unroll
        for (int mk = 1; mk < 64; mk <<= 1) xqv += __shfl_xor(xqv, mk, 64);

        float accv[8];
#pragma unroll
        for (int k = 0; k < 8; ++k) accv[k] = 0.f;
#pragma unroll 4
        for (int d = 0; d < EMB; ++d) {
            float4 wa = *(const float4*)(w + d * NEMB + (lane << 2));
            float4 wb = *(const float4*)(w + d * NEMB + 256 + (lane << 2));
            float xv = __shfl(xd, d, 64);
            accv[0] = fmaf(xv, wa.x, accv[0]);
            accv[1] = fmaf(xv, wa.y, accv[1]);
            accv[2] = fmaf(xv, wa.z, accv[2]);
            accv[3] = fmaf(xv, wa.w, accv[3]);
            accv[4] = fmaf(xv, wb.x, accv[4]);
            accv[5] = fmaf(xv, wb.y, accv[5]);
            accv[6] = fmaf(xv, wb.z, accv[6]);
            accv[7] = fmaf(xv, wb.w, accv[7]);
        }

        float S1 = 3.4e38f, S2 = 3.4e38f; int J1 = 0, J2 = 0;
#pragma unroll
        for (int k = 0; k < 8; ++k) {
            int j = (k < 4) ? ((lane << 2) + k) : (256 + (lane << 2) + k - 4);
            float s = (xqv - 2.f * accv[k]) + wsq_s[j];
            UPD(S1, J1, S2, J2, s, j);
        }
#pragma unroll
        for (int mk = 1; mk < 64; mk <<= 1) {
            float os1 = __shfl_xor(S1, mk, 64); int oj1 = __shfl_xor(J1, mk, 64);
            float os2 = __shfl_xor(S2, mk, 64); int oj2 = __shfl_xor(J2, mk, 64);
            UPD(S1, J1, S2, J2, os1, oj1);
            UPD(S1, J1, S2, J2, os2, oj2);
        }

        int jm = J1;
        if (S2 - S1 < 1e-3f) {
            float w1 = w[lane * NEMB + J1];
            float w2 = w[lane * NEMB + J2];
            double e1 = (double)w1 * (double)w1 - 2.0 * (double)xd * (double)w1;
            double e2 = (double)w2 * (double)w2 - 2.0 * (double)xd * (double)w2;
#pragma unroll
            for (int mk = 1; mk < 64; mk <<= 1) {
                e1 += __shfl_xor(e1, mk, 64);
                e2 += __shfl_xor(e2, mk, 64);
            }
            if (e2 < e1 || (e2 == e1 && J2 < J1)) jm = J2;
        }
        if (lane == 0) out_arg[t0 + m] = (float)jm;
    }
}

// fused: result write + es/cnt accumulation. grid = 65 grp x 32 chunks (2080 blocks).
// float4-vectorized over 4 consecutive tokens. LDS accumulate, atomic flush.
__global__ __launch_bounds__(256) void finish_kernel(
    const float* __restrict__ x, const float* __restrict__ w, const float* __restrict__ arg,
    float* __restrict__ out_result,
    float* __restrict__ es, float* __restrict__ cnt)
{
    __shared__ float wrow[NEMB];
    __shared__ float acc[NEMB];
    const int tid = threadIdx.x;
    const int grp = blockIdx.x >> 5;     // 0..64
    const int chunk = blockIdx.x & 31;

    acc[tid] = 0.f; acc[tid + 256] = 0.f;
    if (grp < 64) {
        wrow[tid] = w[grp * NEMB + tid];
        wrow[tid + 256] = w[grp * NEMB + tid + 256];
    }
    __syncthreads();

    const int tbase = chunk << 12;       // 4096 tokens per chunk
    if (grp < 64) {
        const int d = grp;
#pragma unroll 2
        for (int it = 0; it < 4; ++it) {
            int t = tbase + (it << 10) + (tid << 2);      // 4 consecutive tokens, same b
            int o = (t >> 12) * BSTR + d * 4096 + (t & 4095);
            float4 a4 = *(const float4*)(arg + t);
            float4 x4 = *(const float4*)(x + o);
            int j0 = (int)a4.x, j1 = (int)a4.y, j2 = (int)a4.z, j3 = (int)a4.w;
            atomicAdd(&acc[j0], x4.x);
            atomicAdd(&acc[j1], x4.y);
            atomicAdd(&acc[j2], x4.z);
            atomicAdd(&acc[j3], x4.w);
            float4 r4 = {wrow[j0], wrow[j1], wrow[j2], wrow[j3]};
            *(float4*)(out_result + o) = r4;
        }
    } else {
#pragma unroll 2
        for (int it = 0; it < 4; ++it) {
            int t = tbase + (it << 10) + (tid << 2);
            float4 a4 = *(const float4*)(arg + t);
            atomicAdd(&acc[(int)a4.x], 1.0f);
            atomicAdd(&acc[(int)a4.y], 1.0f);
            atomicAdd(&acc[(int)a4.z], 1.0f);
            atomicAdd(&acc[(int)a4.w], 1.0f);
        }
    }
    __syncthreads();

    float* dst = (grp < 64) ? (es + grp * NEMB) : cnt;
#pragma unroll
    for (int k = 0; k < 2; ++k) {
        int j = tid + (k << 8);
        float v = acc[j];
        if (v != 0.f) atomicAdd(&dst[j], v);
    }
}

// fused finalize: 64 blocks x 512 threads. Block d: computes ncs (redundant, cheap),
// reduces n, writes row d of new_weight/new_embed_avg; block 0 also writes out_ncs.
__global__ void finalize_kernel(const float* __restrict__ cs_in, const float* __restrict__ avg_in,
                                const float* __restrict__ cnt_ws,
                                float* __restrict__ out_w, float* __restrict__ out_ncs,
                                float* __restrict__ avg_io /* es in, new_embed_avg out */) {
    __shared__ float red[NEMB];
    const int j = threadIdx.x;
    const int d = blockIdx.x;
    float c = cnt_ws[j];
    float nidx = (c == 0.f) ? 1.f : c;
    float ncs = DECAYF * cs_in[j] + OMDF * nidx;
    red[j] = ncs;
    __syncthreads();
    for (int s = 256; s > 0; s >>= 1) {
        if (j < s) red[j] += red[j + s];
        __syncthreads();
    }
    float n = red[0];
    float csj = (ncs + EPSF) / (n + (float)NEMB * EPSF) * n;
    int o = d * NEMB + j;
    float esv = avg_io[o];
    float navg = DECAYF * avg_in[o] + OMDF * esv;
    avg_io[o] = navg;
    out_w[o] = navg / csj;
    if (d == 0) out_ncs[j] = ncs;
}

extern "C" void kernel_launch(void* const* d_in, const int* in_sizes, int n_in,
                              void* d_out, int out_size, void* d_ws, size_t ws_size,
                              hipStream_t stream) {
    (void)in_sizes; (void)n_in; (void)out_size; (void)ws_size;
    const float* x   = (const float*)d_in[0];
    const float* w   = (const float*)d_in[1];
    const float* cs  = (const float*)d_in[2];
    const float* avg = (const float*)d_in[3];

    float* out = (float*)d_out;
    float* out_result = out;                 // 8388608
    float* out_arg    = out + 8388608;       // 131072
    float* out_w      = out + 8519680;       // 32768
    float* out_ncs    = out + 8552448;       // 512
    float* out_avg    = out + 8552960;       // 32768 (es accumulates here)

    char* wsb = (char*)d_ws;
    unsigned short* wh = (unsigned short*)wsb;             // 65536 B
    unsigned short* wl = (unsigned short*)(wsb + 65536);   // 65536 B
    float* wsq      = (float*)(wsb + 131072);              // 2048 B
    float* cnt_ws   = (float*)(wsb + 133120);              // 2048 B (counts)

    prep_kernel<<<9, 512, 0, stream>>>(w, wh, wl, wsq, cnt_ws, out_avg);
    vq_main<<<1024, 256, 0, stream>>>(x, w, wh, wl, wsq, out_arg);
    finish_kernel<<<2080, 256, 0, stream>>>(x, w, out_arg, out_result, out_avg, cnt_ws);
    finalize_kernel<<<64, 512, 0, stream>>>(cs, avg, cnt_ws, out_w, out_ncs, out_avg);
}